// Round 8
// baseline (449.455 us; speedup 1.0000x reference)
//
#include <hip/hip_runtime.h>
#include <hip/hip_fp16.h>
#include <math.h>

constexpr int kNodes   = 40000;
constexpr int kEdges   = 640000;
constexpr int kEmb     = 128;
constexpr int kOut     = 256;
constexpr int kTargets = 12;
constexpr int kRadial  = 6;

typedef float        f32x4 __attribute__((ext_vector_type(4)));
typedef unsigned int u32x4 __attribute__((ext_vector_type(4)));

// Address-space-qualified pointer types for global_load_lds.
typedef __attribute__((address_space(1))) const void gvoid;
typedef __attribute__((address_space(3))) void       lvoid;

__device__ __forceinline__ unsigned short f2h(float f) {
  return __half_as_ushort(__float2half(f));   // RTNE
}
__device__ __forceinline__ void mfma_f16(f32x4& c, u32x4 a, u32x4 b) {
  asm volatile("v_mfma_f32_16x16x32_f16 %0, %1, %2, %0" : "+v"(c) : "v"(a), "v"(b));
}

// ---------------------------------------------------------------------------
// Weight prep: f32 -> fp16 MFMA fragment-order images (see R7 comment),
// plus zeroing of the CSR counts array.
// ---------------------------------------------------------------------------
__global__ __launch_bounds__(256) void prep_weights(
    const float* __restrict__ Wup, const float* __restrict__ Wmlp,
    const float* __restrict__ Wfin,
    unsigned short* __restrict__ WtUp, unsigned short* __restrict__ WtM,
    unsigned short* __restrict__ WtFin, int* __restrict__ counts) {
  const int id = blockIdx.x * 256 + threadIdx.x;
  if (id < kNodes) counts[id] = 0;

  if (id < 32768) {                       // W_up image (K=128 -> 4 chunks)
    const int e = id & 7, u = id >> 3;
    const int l = u & 63, j = (u >> 6) & 3, wv = (u >> 8) & 3, c = u >> 10;
    const int n = wv * 64 + j * 16 + (l & 15);
    const int k = c * 32 + (l >> 4) * 8 + e;
    WtUp[id] = f2h(Wup[k * 256 + n]);
    return;
  }
  const int id2 = id - 32768;
  if (id2 < 3 * 65536) {                  // W_mlp images (K=256 -> 8 chunks)
    const int L = id2 >> 16, r = id2 & 65535;
    const int e = r & 7, u = r >> 3;
    const int l = u & 63, j = (u >> 6) & 3, wv = (u >> 8) & 3, c = u >> 10;
    const int n = wv * 64 + j * 16 + (l & 15);
    const int k = c * 32 + (l >> 4) * 8 + e;
    WtM[id2] = f2h(Wmlp[L * 65536 + k * 256 + n]);
    return;
  }
  const int id3 = id2 - 3 * 65536;
  if (id3 < 16 * 256) {                   // W_final^T, targets padded 12->16
    const int n = id3 >> 8, k = id3 & 255;
    WtFin[id3] = (n < kTargets) ? f2h(Wfin[k * kTargets + n]) : (unsigned short)0;
  }
}

// ---------------------------------------------------------------------------
// CSR: histogram (int atomics, L2-resident counts)
// ---------------------------------------------------------------------------
__global__ __launch_bounds__(256) void hist_kernel(const int* __restrict__ idnb,
                                                   int* __restrict__ counts) {
  const int e = blockIdx.x * 256 + threadIdx.x;
  if (e < kEdges) atomicAdd(&counts[idnb[e]], 1);
}

// ---------------------------------------------------------------------------
// CSR: single-block exclusive scan. 1024 threads x 40 contiguous counts each
// (per-wave 10 KB region stays L1-resident across the 40 strided iterations).
// ---------------------------------------------------------------------------
__global__ __launch_bounds__(1024) void scan_block(const int* __restrict__ counts,
                                                   int* __restrict__ offs,
                                                   int* __restrict__ next) {
  __shared__ int sm[1024];
  const int t = threadIdx.x;
  constexpr int C = 40;                    // 1024*40 = 40960 >= kNodes
  const int base = t * C;
  int loc[C];
  int s = 0;
#pragma unroll
  for (int i = 0; i < C; ++i) {
    const int idx = base + i;
    const int v = (idx < kNodes) ? counts[idx] : 0;
    loc[i] = s;                            // local exclusive prefix
    s += v;
  }
  sm[t] = s;
  __syncthreads();
  for (int d = 1; d < 1024; d <<= 1) {
    const int v = (t >= d) ? sm[t - d] : 0;
    __syncthreads();
    sm[t] += v;
    __syncthreads();
  }
  const int excl = (t == 0) ? 0 : sm[t - 1];
#pragma unroll
  for (int i = 0; i < C; ++i) {
    const int idx = base + i;
    if (idx < kNodes) {
      const int e = excl + loc[i];
      offs[idx] = e;
      next[idx] = e;
    }
  }
  if (t == 0) offs[kNodes] = kEdges;
}

__global__ __launch_bounds__(256) void fill_kernel(const int* __restrict__ idnb,
                                                   int* __restrict__ next,
                                                   int* __restrict__ edgeIdx) {
  const int e = blockIdx.x * 256 + threadIdx.x;
  if (e < kEdges) {
    const int p = atomicAdd(&next[idnb[e]], 1);
    edgeIdx[p] = e;
  }
}

// ---------------------------------------------------------------------------
// FUSED gather + MLP + final projection. 625 blocks x 256 thr, 64 nodes/block.
//   Phase A: 8 groups of 32 lanes; group g gathers nodes g*8..g*8+7 (lane owns
//            4 of 128 dims), accumulating f32, writing fp16 into act LDS.
//            x loads are nontemporal (read-once 327 MB stream).
//   Phase B: 4-layer MLP, wave-private fragment-order weight DMA
//            (global_load_lds w16, counted vmcnt, no per-chunk barriers).
//   Phase C: act @ WtFin^T via MFMA, k-split across waves, LDS reduce.
// Layer-0 chunk-0 weight DMA is issued at kernel entry and lands during
// Phase A for free. LDS: act 34.0K + sB 32.8K + wLds 3.1K = 69.9K -> 2 blk/CU.
// Fusion rationale: gather is HBM-bound, MLP is MFMA-bound; across blocks the
// two phases overlap (sum -> max).
// ---------------------------------------------------------------------------
__global__ __launch_bounds__(256) void gather_mlp(
    const float* __restrict__ x, const float* __restrict__ rbf,
    const int* __restrict__ offs, const int* __restrict__ edgeIdx,
    const float* __restrict__ W_rbf,
    const unsigned short* __restrict__ WtUp,
    const unsigned short* __restrict__ WtM,
    const unsigned short* __restrict__ WtFin,
    const float* __restrict__ b_mlp, float* __restrict__ out) {
  __shared__ unsigned short act[64][266];   // odd word-pitch: conflict-light
  __shared__ unsigned short sB[2][8192];    // 2 x 16 KB, fragment order
  __shared__ float wLds[kRadial * kEmb];

  const int tid     = threadIdx.x;
  const int rowBase = blockIdx.x * 64;
  const int w    = tid >> 6;
  const int lane = tid & 63;
  const int lrow = lane & 15;
  const int kgrp = lane >> 4;

  // Issue layer-0 chunk-0 weight DMA now; it completes during the gather.
#pragma unroll
  for (int j = 0; j < 4; ++j)
    __builtin_amdgcn_global_load_lds(
        (gvoid*)(WtUp + w * 2048 + j * 512 + lane * 8),
        (lvoid*)&sB[0][w * 2048 + j * 512], 16, 0, 0);

  for (int i = tid; i < kRadial * kEmb; i += 256) wLds[i] = W_rbf[i];
  __syncthreads();

  // ---------- Phase A: gather ----------
  {
    const int sub = tid & 31;
    const int grp = tid >> 5;               // 0..7
    f32x4 wreg[kRadial];
#pragma unroll
    for (int j = 0; j < kRadial; ++j)
      wreg[j] = *(const f32x4*)(wLds + j * kEmb + sub * 4);

    for (int q = 0; q < 8; ++q) {
      const int n = rowBase + grp * 8 + q;
      const int beg = offs[n], end = offs[n + 1];
      f32x4 acc = {0.f, 0.f, 0.f, 0.f};
      for (int i = beg; i < end; ++i) {
        const int e = edgeIdx[i];
        const float* rr = rbf + (size_t)e * kRadial;
        const float r0 = rr[0], r1 = rr[1], r2 = rr[2];
        const float r3 = rr[3], r4 = rr[4], r5 = rr[5];
        const f32x4 xv = __builtin_nontemporal_load(
            (const f32x4*)(x + (size_t)e * kEmb + sub * 4));
        const f32x4 g = r0 * wreg[0] + r1 * wreg[1] + r2 * wreg[2] +
                        r3 * wreg[3] + r4 * wreg[4] + r5 * wreg[5];
        acc += g * xv;
      }
      ushort2 h0, h1;
      h0.x = f2h(acc.x); h0.y = f2h(acc.y);
      h1.x = f2h(acc.z); h1.y = f2h(acc.w);
      *(ushort2*)&act[grp * 8 + q][sub * 4]     = h0;
      *(ushort2*)&act[grp * 8 + q][sub * 4 + 2] = h1;
    }
  }
  __syncthreads();   // act[*, 0..127] ready for layer 0

  // ---------- Phase B: MLP ----------
  for (int l = 0; l < 4; ++l) {
    const int nc = (l == 0) ? 4 : 8;
    const unsigned short* W = (l == 0) ? WtUp : WtM + (size_t)(l - 1) * 65536;

    // Preload bias into VGPRs and pin (keeps in-loop vmcnt counts exact).
    float bj[4] = {0.f, 0.f, 0.f, 0.f};
    if (l >= 1) {
      const float* bias = b_mlp + (size_t)(l - 1) * kOut;
#pragma unroll
      for (int j = 0; j < 4; ++j) bj[j] = bias[w * 64 + j * 16 + lrow];
      asm volatile("" ::"v"(bj[0]), "v"(bj[1]), "v"(bj[2]), "v"(bj[3]));
    }

    if (l >= 1) {
      // Prologue: chunk 0 of this layer (overlaps previous layer's epilogue).
#pragma unroll
      for (int j = 0; j < 4; ++j)
        __builtin_amdgcn_global_load_lds(
            (gvoid*)(W + w * 2048 + j * 512 + lane * 8),
            (lvoid*)&sB[0][w * 2048 + j * 512], 16, 0, 0);
    }

    f32x4 acc[4][4];
#pragma unroll
    for (int i = 0; i < 4; ++i)
#pragma unroll
      for (int j = 0; j < 4; ++j) acc[i][j] = f32x4{0.f, 0.f, 0.f, 0.f};

    int buf = 0;
    for (int c = 0; c < nc; ++c) {
      if (c + 1 < nc) {
        const unsigned short* Wn = W + (size_t)(c + 1) * 8192;
#pragma unroll
        for (int j = 0; j < 4; ++j)
          __builtin_amdgcn_global_load_lds(
              (gvoid*)(Wn + w * 2048 + j * 512 + lane * 8),
              (lvoid*)&sB[buf ^ 1][w * 2048 + j * 512], 16, 0, 0);
        asm volatile("s_waitcnt vmcnt(4)" ::: "memory");  // chunk c landed
      } else {
        asm volatile("s_waitcnt vmcnt(0)" ::: "memory");
      }
      u32x4 a[4], b[4];
#pragma unroll
      for (int i = 0; i < 4; ++i)
        a[i] = *(const u32x4*)&act[i * 16 + lrow][c * 32 + kgrp * 8];
#pragma unroll
      for (int j = 0; j < 4; ++j)
        b[j] = *(const u32x4*)&sB[buf][w * 2048 + j * 512 + lane * 8];
      __builtin_amdgcn_s_setprio(1);
#pragma unroll
      for (int j = 0; j < 4; ++j)
#pragma unroll
        for (int i = 0; i < 4; ++i) mfma_f16(acc[i][j], a[i], b[j]);
      __builtin_amdgcn_s_setprio(0);
      buf ^= 1;
    }

    __syncthreads();   // all waves done reading act for this layer
#pragma unroll
    for (int j = 0; j < 4; ++j) {
      const int col = w * 64 + j * 16 + lrow;
#pragma unroll
      for (int i = 0; i < 4; ++i) {
#pragma unroll
        for (int r = 0; r < 4; ++r) {
          float v = acc[i][j][r];
          if (l >= 1) {
            v += bj[j];
            v = v / (1.f + __expf(-v));   // silu
          }
          act[i * 16 + kgrp * 4 + r][col] = f2h(v);
        }
      }
    }
    __syncthreads();
  }

  // ---------- Phase C: final projection ----------
  // sPart inner dim MUST be 16 (MFMA epilogue writes cols 0..15; 12 real + 4
  // zero-padded). [64][16] floats = exactly 16 KB = sB[1].
  unsigned short (*sWf)[266] = (unsigned short(*)[266]) & sB[0][0];  // 8.5 KB
  float (*sPart)[64][16]     = (float(*)[64][16]) & sB[1][0];        // 16 KB
#pragma unroll
  for (int p = 0; p < 2; ++p) {
    const int q = p * 256 + tid;
    const int n = q >> 5, c = q & 31;
    *(u32x4*)&sWf[n][c * 8] = *(const u32x4*)(WtFin + (size_t)n * 256 + c * 8);
  }
  __syncthreads();

  f32x4 accF[4];
#pragma unroll
  for (int i = 0; i < 4; ++i) accF[i] = f32x4{0.f, 0.f, 0.f, 0.f};
#pragma unroll
  for (int s = 0; s < 2; ++s) {
    const int cc = w * 2 + s;
    const u32x4 b = *(const u32x4*)&sWf[lrow][cc * 32 + kgrp * 8];
#pragma unroll
    for (int i = 0; i < 4; ++i) {
      const u32x4 a = *(const u32x4*)&act[i * 16 + lrow][cc * 32 + kgrp * 8];
      mfma_f16(accF[i], a, b);
    }
  }
#pragma unroll
  for (int i = 0; i < 4; ++i)
#pragma unroll
    for (int r = 0; r < 4; ++r)
      sPart[w][i * 16 + kgrp * 4 + r][lrow] = accF[i][r];
  __syncthreads();

  for (int q = tid; q < 64 * kTargets; q += 256) {
    const int r = q / kTargets, t = q % kTargets;
    out[(size_t)(rowBase + r) * kTargets + t] =
        sPart[0][r][t] + sPart[1][r][t] + sPart[2][r][t] + sPart[3][r][t];
  }
}

// ---------------------------------------------------------------------------
extern "C" void kernel_launch(void* const* d_in, const int* in_sizes, int n_in,
                              void* d_out, int out_size, void* d_ws, size_t ws_size,
                              hipStream_t stream) {
  const float* x      = (const float*)d_in[1];
  const float* rbf    = (const float*)d_in[2];
  const int*   idnb   = (const int*)d_in[3];
  const float* W_rbf  = (const float*)d_in[4];
  const float* W_up   = (const float*)d_in[5];
  const float* W_mlp  = (const float*)d_in[6];
  const float* b_mlp  = (const float*)d_in[7];
  const float* W_fin  = (const float*)d_in[8];
  float* out = (float*)d_out;

  char* wp = (char*)d_ws;
  auto alloc = [&](size_t bytes) -> void* {
    void* r = wp;
    wp += (bytes + 255) & ~(size_t)255;
    return r;
  };
  unsigned short* WtUp   = (unsigned short*)alloc(32768 * 2);
  unsigned short* WtM    = (unsigned short*)alloc(3 * 65536 * 2);
  unsigned short* WtFin  = (unsigned short*)alloc(16 * 256 * 2);
  int* counts  = (int*)alloc((size_t)kNodes * 4);
  int* offs    = (int*)alloc((size_t)(kNodes + 8) * 4);
  int* next    = (int*)alloc((size_t)kNodes * 4);
  int* edgeIdx = (int*)alloc((size_t)kEdges * 4);

  constexpr int prepElems = 32768 + 3 * 65536 + 16 * 256;  // 233472

  // 1: weight images + counts zeroing.
  prep_weights<<<(prepElems + 255) / 256, 256, 0, stream>>>(
      W_up, W_mlp, W_fin, WtUp, WtM, WtFin, counts);
  // 2-4: CSR build.
  hist_kernel<<<kEdges / 256, 256, 0, stream>>>(idnb, counts);
  scan_block<<<1, 1024, 0, stream>>>(counts, offs, next);
  fill_kernel<<<kEdges / 256, 256, 0, stream>>>(idnb, next, edgeIdx);
  // 5: fused gather + MLP + projection.
  gather_mlp<<<kNodes / 64, 256, 0, stream>>>(x, rbf, offs, edgeIdx, W_rbf,
                                              WtUp, WtM, WtFin, b_mlp, out);
}

// Round 9
// 277.549 us; speedup vs baseline: 1.6194x; 1.6194x over previous
//
#include <hip/hip_runtime.h>
#include <hip/hip_fp16.h>
#include <math.h>

constexpr int kNodes   = 40000;
constexpr int kEdges   = 640000;
constexpr int kEmb     = 128;
constexpr int kOut     = 256;
constexpr int kTargets = 12;
constexpr int kRadial  = 6;

typedef float        f32x4 __attribute__((ext_vector_type(4)));
typedef unsigned int u32x4 __attribute__((ext_vector_type(4)));

// Address-space-qualified pointer types for global_load_lds.
typedef __attribute__((address_space(1))) const void gvoid;
typedef __attribute__((address_space(3))) void       lvoid;

__device__ __forceinline__ unsigned short f2h(float f) {
  return __half_as_ushort(__float2half(f));   // RTNE
}
__device__ __forceinline__ void mfma_f16(f32x4& c, u32x4 a, u32x4 b) {
  asm volatile("v_mfma_f32_16x16x32_f16 %0, %1, %2, %0" : "+v"(c) : "v"(a), "v"(b));
}

// ---------------------------------------------------------------------------
// Weight prep: f32 -> fp16 MFMA fragment-order images + CSR counts zeroing.
// ---------------------------------------------------------------------------
__global__ __launch_bounds__(256) void prep_weights(
    const float* __restrict__ Wup, const float* __restrict__ Wmlp,
    const float* __restrict__ Wfin,
    unsigned short* __restrict__ WtUp, unsigned short* __restrict__ WtM,
    unsigned short* __restrict__ WtFin, int* __restrict__ counts) {
  const int id = blockIdx.x * 256 + threadIdx.x;
  if (id < kNodes) counts[id] = 0;

  if (id < 32768) {                       // W_up image (K=128 -> 4 chunks)
    const int e = id & 7, u = id >> 3;
    const int l = u & 63, j = (u >> 6) & 3, wv = (u >> 8) & 3, c = u >> 10;
    const int n = wv * 64 + j * 16 + (l & 15);
    const int k = c * 32 + (l >> 4) * 8 + e;
    WtUp[id] = f2h(Wup[k * 256 + n]);
    return;
  }
  const int id2 = id - 32768;
  if (id2 < 3 * 65536) {                  // W_mlp images (K=256 -> 8 chunks)
    const int L = id2 >> 16, r = id2 & 65535;
    const int e = r & 7, u = r >> 3;
    const int l = u & 63, j = (u >> 6) & 3, wv = (u >> 8) & 3, c = u >> 10;
    const int n = wv * 64 + j * 16 + (l & 15);
    const int k = c * 32 + (l >> 4) * 8 + e;
    WtM[id2] = f2h(Wmlp[L * 65536 + k * 256 + n]);
    return;
  }
  const int id3 = id2 - 3 * 65536;
  if (id3 < 16 * 256) {                   // W_final^T, targets padded 12->16
    const int n = id3 >> 8, k = id3 & 255;
    WtFin[id3] = (n < kTargets) ? f2h(Wfin[k * kTargets + n]) : (unsigned short)0;
  }
}

// ---------------------------------------------------------------------------
// CSR build
// ---------------------------------------------------------------------------
__global__ __launch_bounds__(256) void hist_kernel(const int* __restrict__ idnb,
                                                   int* __restrict__ counts) {
  const int e = blockIdx.x * 256 + threadIdx.x;
  if (e < kEdges) atomicAdd(&counts[idnb[e]], 1);
}

// Single-block exclusive scan: 1024 threads x 40 contiguous counts each.
__global__ __launch_bounds__(1024) void scan_block(const int* __restrict__ counts,
                                                   int* __restrict__ offs,
                                                   int* __restrict__ next) {
  __shared__ int sm[1024];
  const int t = threadIdx.x;
  constexpr int C = 40;                    // 1024*40 = 40960 >= kNodes
  const int base = t * C;
  int loc[C];
  int s = 0;
#pragma unroll
  for (int i = 0; i < C; ++i) {
    const int idx = base + i;
    const int v = (idx < kNodes) ? counts[idx] : 0;
    loc[i] = s;                            // local exclusive prefix
    s += v;
  }
  sm[t] = s;
  __syncthreads();
  for (int d = 1; d < 1024; d <<= 1) {
    const int v = (t >= d) ? sm[t - d] : 0;
    __syncthreads();
    sm[t] += v;
    __syncthreads();
  }
  const int excl = (t == 0) ? 0 : sm[t - 1];
#pragma unroll
  for (int i = 0; i < C; ++i) {
    const int idx = base + i;
    if (idx < kNodes) {
      const int e = excl + loc[i];
      offs[idx] = e;
      next[idx] = e;
    }
  }
  if (t == 0) offs[kNodes] = kEdges;
}

__global__ __launch_bounds__(256) void fill_kernel(const int* __restrict__ idnb,
                                                   int* __restrict__ next,
                                                   int* __restrict__ edgeIdx) {
  const int e = blockIdx.x * 256 + threadIdx.x;
  if (e < kEdges) {
    const int p = atomicAdd(&next[idnb[e]], 1);
    edgeIdx[p] = e;
  }
}

// ---------------------------------------------------------------------------
// Gather: 32 lanes per node, 8 nodes per block, HIGH occupancy (separate
// kernel, ~20 VGPR -> many waves/CU; R8 proved fusing this kills it).
// 2-wide edge unroll with DUAL accumulators: two independent
// edgeIdx->x dependence chains per iteration => ~2x in-flight 512B rows.
// ---------------------------------------------------------------------------
__global__ __launch_bounds__(256) void gather_kernel(
    const float* __restrict__ x, const float* __restrict__ rbf,
    const int* __restrict__ offs, const int* __restrict__ edgeIdx,
    const float* __restrict__ W_rbf, unsigned short* __restrict__ pooled) {
  __shared__ float wLds[kRadial * kEmb];
  for (int i = threadIdx.x; i < kRadial * kEmb; i += 256) wLds[i] = W_rbf[i];
  __syncthreads();

  const int sub = threadIdx.x & 31;
  const int n   = blockIdx.x * 8 + (threadIdx.x >> 5);

  f32x4 w[kRadial];
#pragma unroll
  for (int j = 0; j < kRadial; ++j)
    w[j] = *(const f32x4*)(wLds + j * kEmb + sub * 4);

  const int beg = offs[n], end = offs[n + 1];
  f32x4 acc0 = {0.f, 0.f, 0.f, 0.f};
  f32x4 acc1 = {0.f, 0.f, 0.f, 0.f};

  int i = beg;
  for (; i + 1 < end; i += 2) {
    const int e0 = edgeIdx[i];
    const int e1 = edgeIdx[i + 1];
    const float2 a0 = *(const float2*)(rbf + (size_t)e0 * kRadial);
    const float2 b0 = *(const float2*)(rbf + (size_t)e0 * kRadial + 2);
    const float2 c0 = *(const float2*)(rbf + (size_t)e0 * kRadial + 4);
    const float2 a1 = *(const float2*)(rbf + (size_t)e1 * kRadial);
    const float2 b1 = *(const float2*)(rbf + (size_t)e1 * kRadial + 2);
    const float2 c1 = *(const float2*)(rbf + (size_t)e1 * kRadial + 4);
    const f32x4 xv0 = __builtin_nontemporal_load(
        (const f32x4*)(x + (size_t)e0 * kEmb + sub * 4));
    const f32x4 xv1 = __builtin_nontemporal_load(
        (const f32x4*)(x + (size_t)e1 * kEmb + sub * 4));
    const f32x4 g0 = a0.x * w[0] + a0.y * w[1] + b0.x * w[2] +
                     b0.y * w[3] + c0.x * w[4] + c0.y * w[5];
    const f32x4 g1 = a1.x * w[0] + a1.y * w[1] + b1.x * w[2] +
                     b1.y * w[3] + c1.x * w[4] + c1.y * w[5];
    acc0 += g0 * xv0;
    acc1 += g1 * xv1;
  }
  if (i < end) {   // odd tail
    const int e0 = edgeIdx[i];
    const float2 a0 = *(const float2*)(rbf + (size_t)e0 * kRadial);
    const float2 b0 = *(const float2*)(rbf + (size_t)e0 * kRadial + 2);
    const float2 c0 = *(const float2*)(rbf + (size_t)e0 * kRadial + 4);
    const f32x4 xv0 = __builtin_nontemporal_load(
        (const f32x4*)(x + (size_t)e0 * kEmb + sub * 4));
    const f32x4 g0 = a0.x * w[0] + a0.y * w[1] + b0.x * w[2] +
                     b0.y * w[3] + c0.x * w[4] + c0.y * w[5];
    acc0 += g0 * xv0;
  }
  const f32x4 acc = acc0 + acc1;

  ushort4 hv;
  hv.x = f2h(acc.x);
  hv.y = f2h(acc.y);
  hv.z = f2h(acc.z);
  hv.w = f2h(acc.w);
  *(ushort4*)(pooled + (size_t)n * kEmb + sub * 4) = hv;
}

// ---------------------------------------------------------------------------
// Fused node MLP (R7 structure): wave-private fragment-order weight DMA
// (global_load_lds w16), counted vmcnt, no per-chunk barriers.
// ---------------------------------------------------------------------------
__global__ __launch_bounds__(256) void fused_mlp(
    const unsigned short* __restrict__ pooled,
    const unsigned short* __restrict__ WtUp,
    const unsigned short* __restrict__ WtM,
    const unsigned short* __restrict__ WtFin,
    const float* __restrict__ b_mlp, float* __restrict__ out) {
  __shared__ unsigned short act[64][266];   // odd word-pitch: conflict-light
  __shared__ unsigned short sB[2][8192];    // 2 x 16 KB, fragment order

  const int tid     = threadIdx.x;
  const int rowBase = blockIdx.x * 64;
  const int w    = tid >> 6;
  const int lane = tid & 63;
  const int lrow = lane & 15;
  const int kgrp = lane >> 4;

  // Stage pooled -> act (64 x 128 fp16).
#pragma unroll
  for (int p = 0; p < 4; ++p) {
    const int q = p * 256 + tid;
    const int r = q >> 4, c = q & 15;
    *(u32x4*)&act[r][c * 8] =
        *(const u32x4*)(pooled + (size_t)(rowBase + r) * kEmb + c * 8);
  }
  __syncthreads();

  for (int l = 0; l < 4; ++l) {
    const int nc = (l == 0) ? 4 : 8;
    const unsigned short* W = (l == 0) ? WtUp : WtM + (size_t)(l - 1) * 65536;

    // Preload bias into VGPRs and pin (keeps in-loop vmcnt counts exact).
    float bj[4] = {0.f, 0.f, 0.f, 0.f};
    if (l >= 1) {
      const float* bias = b_mlp + (size_t)(l - 1) * kOut;
#pragma unroll
      for (int j = 0; j < 4; ++j) bj[j] = bias[w * 64 + j * 16 + lrow];
      asm volatile("" ::"v"(bj[0]), "v"(bj[1]), "v"(bj[2]), "v"(bj[3]));
    }

    // Prologue: stage chunk 0 -> buf 0 (wave-private fragments).
#pragma unroll
    for (int j = 0; j < 4; ++j)
      __builtin_amdgcn_global_load_lds(
          (gvoid*)(W + w * 2048 + j * 512 + lane * 8),
          (lvoid*)&sB[0][w * 2048 + j * 512], 16, 0, 0);

    f32x4 acc[4][4];
#pragma unroll
    for (int i = 0; i < 4; ++i)
#pragma unroll
      for (int j = 0; j < 4; ++j) acc[i][j] = f32x4{0.f, 0.f, 0.f, 0.f};

    int buf = 0;
    for (int c = 0; c < nc; ++c) {
      if (c + 1 < nc) {
        const unsigned short* Wn = W + (size_t)(c + 1) * 8192;
#pragma unroll
        for (int j = 0; j < 4; ++j)
          __builtin_amdgcn_global_load_lds(
              (gvoid*)(Wn + w * 2048 + j * 512 + lane * 8),
              (lvoid*)&sB[buf ^ 1][w * 2048 + j * 512], 16, 0, 0);
        asm volatile("s_waitcnt vmcnt(4)" ::: "memory");  // chunk c landed
      } else {
        asm volatile("s_waitcnt vmcnt(0)" ::: "memory");
      }
      u32x4 a[4], b[4];
#pragma unroll
      for (int i = 0; i < 4; ++i)
        a[i] = *(const u32x4*)&act[i * 16 + lrow][c * 32 + kgrp * 8];
#pragma unroll
      for (int j = 0; j < 4; ++j)
        b[j] = *(const u32x4*)&sB[buf][w * 2048 + j * 512 + lane * 8];
      __builtin_amdgcn_s_setprio(1);
#pragma unroll
      for (int j = 0; j < 4; ++j)
#pragma unroll
        for (int i = 0; i < 4; ++i) mfma_f16(acc[i][j], a[i], b[j]);
      __builtin_amdgcn_s_setprio(0);
      buf ^= 1;
    }

    __syncthreads();   // all waves done reading act for this layer
#pragma unroll
    for (int j = 0; j < 4; ++j) {
      const int col = w * 64 + j * 16 + lrow;
#pragma unroll
      for (int i = 0; i < 4; ++i) {
#pragma unroll
        for (int r = 0; r < 4; ++r) {
          float v = acc[i][j][r];
          if (l >= 1) {
            v += bj[j];
            v = v / (1.f + __expf(-v));   // silu
          }
          act[i * 16 + kgrp * 4 + r][col] = f2h(v);
        }
      }
    }
    __syncthreads();
  }

  // Final projection: act[64,256] @ WtFin^T[16,256].
  // sPart inner dim MUST be 16 (epilogue writes cols 0..15). 16 KB = sB[1].
  unsigned short (*sWf)[266] = (unsigned short(*)[266]) & sB[0][0];  // 8.5 KB
  float (*sPart)[64][16]     = (float(*)[64][16]) & sB[1][0];        // 16 KB
#pragma unroll
  for (int p = 0; p < 2; ++p) {
    const int q = p * 256 + tid;
    const int n = q >> 5, c = q & 31;
    *(u32x4*)&sWf[n][c * 8] = *(const u32x4*)(WtFin + (size_t)n * 256 + c * 8);
  }
  __syncthreads();

  f32x4 accF[4];
#pragma unroll
  for (int i = 0; i < 4; ++i) accF[i] = f32x4{0.f, 0.f, 0.f, 0.f};
#pragma unroll
  for (int s = 0; s < 2; ++s) {
    const int cc = w * 2 + s;
    const u32x4 b = *(const u32x4*)&sWf[lrow][cc * 32 + kgrp * 8];
#pragma unroll
    for (int i = 0; i < 4; ++i) {
      const u32x4 a = *(const u32x4*)&act[i * 16 + lrow][cc * 32 + kgrp * 8];
      mfma_f16(accF[i], a, b);
    }
  }
#pragma unroll
  for (int i = 0; i < 4; ++i)
#pragma unroll
    for (int r = 0; r < 4; ++r)
      sPart[w][i * 16 + kgrp * 4 + r][lrow] = accF[i][r];
  __syncthreads();

  for (int q = tid; q < 64 * kTargets; q += 256) {
    const int r = q / kTargets, t = q % kTargets;
    out[(size_t)(rowBase + r) * kTargets + t] =
        sPart[0][r][t] + sPart[1][r][t] + sPart[2][r][t] + sPart[3][r][t];
  }
}

// ---------------------------------------------------------------------------
extern "C" void kernel_launch(void* const* d_in, const int* in_sizes, int n_in,
                              void* d_out, int out_size, void* d_ws, size_t ws_size,
                              hipStream_t stream) {
  const float* x      = (const float*)d_in[1];
  const float* rbf    = (const float*)d_in[2];
  const int*   idnb   = (const int*)d_in[3];
  const float* W_rbf  = (const float*)d_in[4];
  const float* W_up   = (const float*)d_in[5];
  const float* W_mlp  = (const float*)d_in[6];
  const float* b_mlp  = (const float*)d_in[7];
  const float* W_fin  = (const float*)d_in[8];
  float* out = (float*)d_out;

  char* wp = (char*)d_ws;
  auto alloc = [&](size_t bytes) -> void* {
    void* r = wp;
    wp += (bytes + 255) & ~(size_t)255;
    return r;
  };
  unsigned short* pooled = (unsigned short*)alloc((size_t)kNodes * kEmb * 2);
  unsigned short* WtUp   = (unsigned short*)alloc(32768 * 2);
  unsigned short* WtM    = (unsigned short*)alloc(3 * 65536 * 2);
  unsigned short* WtFin  = (unsigned short*)alloc(16 * 256 * 2);
  int* counts  = (int*)alloc((size_t)kNodes * 4);
  int* offs    = (int*)alloc((size_t)(kNodes + 8) * 4);
  int* next    = (int*)alloc((size_t)kNodes * 4);
  int* edgeIdx = (int*)alloc((size_t)kEdges * 4);

  constexpr int prepElems = 32768 + 3 * 65536 + 16 * 256;  // 233472

  // 1: weight images + counts zeroing.
  prep_weights<<<(prepElems + 255) / 256, 256, 0, stream>>>(
      W_up, W_mlp, W_fin, WtUp, WtM, WtFin, counts);
  // 2-4: CSR build.
  hist_kernel<<<kEdges / 256, 256, 0, stream>>>(idnb, counts);
  scan_block<<<1, 1024, 0, stream>>>(counts, offs, next);
  fill_kernel<<<kEdges / 256, 256, 0, stream>>>(idnb, next, edgeIdx);
  // 5: gather (high occupancy, 2-wide pipelined).
  gather_kernel<<<kNodes / 8, 256, 0, stream>>>(x, rbf, offs, edgeIdx, W_rbf,
                                                pooled);
  // 6: fused node MLP + projection.
  fused_mlp<<<kNodes / 64, 256, 0, stream>>>(pooled, WtUp, WtM, WtFin, b_mlp,
                                             out);
}

// Round 10
// 222.092 us; speedup vs baseline: 2.0237x; 1.2497x over previous
//
#include <hip/hip_runtime.h>
#include <hip/hip_fp16.h>
#include <math.h>

constexpr int kNodes   = 40000;
constexpr int kEdges   = 640000;
constexpr int kEmb     = 128;
constexpr int kOut     = 256;
constexpr int kTargets = 12;
constexpr int kRadial  = 6;

typedef float        f32x4 __attribute__((ext_vector_type(4)));
typedef unsigned int u32x4 __attribute__((ext_vector_type(4)));

// Address-space-qualified pointer types for global_load_lds.
typedef __attribute__((address_space(1))) const void gvoid;
typedef __attribute__((address_space(3))) void       lvoid;

__device__ __forceinline__ unsigned short f2h(float f) {
  return __half_as_ushort(__float2half(f));   // RTNE
}
__device__ __forceinline__ void mfma_f16(f32x4& c, u32x4 a, u32x4 b) {
  asm volatile("v_mfma_f32_16x16x32_f16 %0, %1, %2, %0" : "+v"(c) : "v"(a), "v"(b));
}

// ---------------------------------------------------------------------------
// Weight prep: f32 -> fp16 MFMA fragment-order images + CSR counts zeroing.
// ---------------------------------------------------------------------------
__global__ __launch_bounds__(256) void prep_weights(
    const float* __restrict__ Wup, const float* __restrict__ Wmlp,
    const float* __restrict__ Wfin,
    unsigned short* __restrict__ WtUp, unsigned short* __restrict__ WtM,
    unsigned short* __restrict__ WtFin, int* __restrict__ counts) {
  const int id = blockIdx.x * 256 + threadIdx.x;
  if (id < kNodes) counts[id] = 0;

  if (id < 32768) {                       // W_up image (K=128 -> 4 chunks)
    const int e = id & 7, u = id >> 3;
    const int l = u & 63, j = (u >> 6) & 3, wv = (u >> 8) & 3, c = u >> 10;
    const int n = wv * 64 + j * 16 + (l & 15);
    const int k = c * 32 + (l >> 4) * 8 + e;
    WtUp[id] = f2h(Wup[k * 256 + n]);
    return;
  }
  const int id2 = id - 32768;
  if (id2 < 3 * 65536) {                  // W_mlp images (K=256 -> 8 chunks)
    const int L = id2 >> 16, r = id2 & 65535;
    const int e = r & 7, u = r >> 3;
    const int l = u & 63, j = (u >> 6) & 3, wv = (u >> 8) & 3, c = u >> 10;
    const int n = wv * 64 + j * 16 + (l & 15);
    const int k = c * 32 + (l >> 4) * 8 + e;
    WtM[id2] = f2h(Wmlp[L * 65536 + k * 256 + n]);
    return;
  }
  const int id3 = id2 - 3 * 65536;
  if (id3 < 16 * 256) {                   // W_final^T, targets padded 12->16
    const int n = id3 >> 8, k = id3 & 255;
    WtFin[id3] = (n < kTargets) ? f2h(Wfin[k * kTargets + n]) : (unsigned short)0;
  }
}

// ---------------------------------------------------------------------------
// CSR build — all passes MULTI-BLOCK (R9 lesson: a single-block scan on the
// critical path serializes the grid behind one CU, ~60 us).
// ---------------------------------------------------------------------------
__global__ __launch_bounds__(256) void hist_kernel(const int* __restrict__ idnb,
                                                   int* __restrict__ counts) {
  const int e = blockIdx.x * 256 + threadIdx.x;
  if (e < kEdges) atomicAdd(&counts[idnb[e]], 1);
}

__global__ __launch_bounds__(256) void scan_pass1(const int* __restrict__ counts,
                                                  int* __restrict__ bsum) {
  __shared__ int sm[256];
  const int idx = blockIdx.x * 256 + threadIdx.x;
  sm[threadIdx.x] = (idx < kNodes) ? counts[idx] : 0;
  __syncthreads();
  for (int d = 128; d > 0; d >>= 1) {
    if (threadIdx.x < d) sm[threadIdx.x] += sm[threadIdx.x + d];
    __syncthreads();
  }
  if (threadIdx.x == 0) bsum[blockIdx.x] = sm[0];
}

// Each block reduces the preceding block-sums itself (L2-resident), then
// local exclusive scan.
__global__ __launch_bounds__(256) void scan_pass3(const int* __restrict__ counts,
                                                  const int* __restrict__ bsum,
                                                  int* __restrict__ offs,
                                                  int* __restrict__ next,
                                                  int nblk) {
  __shared__ int sm[256];
  __shared__ int base;
  const int t = threadIdx.x;
  sm[t] = (t < nblk && t < (int)blockIdx.x) ? bsum[t] : 0;
  __syncthreads();
  for (int d = 128; d > 0; d >>= 1) {
    if (t < d) sm[t] += sm[t + d];
    __syncthreads();
  }
  if (t == 0) base = sm[0];
  __syncthreads();

  const int idx = blockIdx.x * 256 + t;
  const int v = (idx < kNodes) ? counts[idx] : 0;
  sm[t] = v;
  __syncthreads();
  for (int d = 1; d < 256; d <<= 1) {
    const int xsh = (t >= d) ? sm[t - d] : 0;
    __syncthreads();
    sm[t] += xsh;
    __syncthreads();
  }
  if (idx < kNodes) {
    const int e = base + sm[t] - v;   // exclusive prefix
    offs[idx] = e;
    next[idx] = e;
  }
  if (blockIdx.x == 0 && t == 0) offs[kNodes] = kEdges;
}

__global__ __launch_bounds__(256) void fill_kernel(const int* __restrict__ idnb,
                                                   int* __restrict__ next,
                                                   int* __restrict__ edgeIdx) {
  const int e = blockIdx.x * 256 + threadIdx.x;
  if (e < kEdges) {
    const int p = atomicAdd(&next[idnb[e]], 1);
    edgeIdx[p] = e;
  }
}

// ---------------------------------------------------------------------------
// Gather: 32 lanes per node, 8 nodes per block, high occupancy.
// 2-wide edge unroll with dual accumulators (two independent edgeIdx->x
// dependence chains per iteration => ~2x in-flight 512B rows).
// ---------------------------------------------------------------------------
__global__ __launch_bounds__(256) void gather_kernel(
    const float* __restrict__ x, const float* __restrict__ rbf,
    const int* __restrict__ offs, const int* __restrict__ edgeIdx,
    const float* __restrict__ W_rbf, unsigned short* __restrict__ pooled) {
  __shared__ float wLds[kRadial * kEmb];
  for (int i = threadIdx.x; i < kRadial * kEmb; i += 256) wLds[i] = W_rbf[i];
  __syncthreads();

  const int sub = threadIdx.x & 31;
  const int n   = blockIdx.x * 8 + (threadIdx.x >> 5);

  f32x4 w[kRadial];
#pragma unroll
  for (int j = 0; j < kRadial; ++j)
    w[j] = *(const f32x4*)(wLds + j * kEmb + sub * 4);

  const int beg = offs[n], end = offs[n + 1];
  f32x4 acc0 = {0.f, 0.f, 0.f, 0.f};
  f32x4 acc1 = {0.f, 0.f, 0.f, 0.f};

  int i = beg;
  for (; i + 1 < end; i += 2) {
    const int e0 = edgeIdx[i];
    const int e1 = edgeIdx[i + 1];
    const float2 a0 = *(const float2*)(rbf + (size_t)e0 * kRadial);
    const float2 b0 = *(const float2*)(rbf + (size_t)e0 * kRadial + 2);
    const float2 c0 = *(const float2*)(rbf + (size_t)e0 * kRadial + 4);
    const float2 a1 = *(const float2*)(rbf + (size_t)e1 * kRadial);
    const float2 b1 = *(const float2*)(rbf + (size_t)e1 * kRadial + 2);
    const float2 c1 = *(const float2*)(rbf + (size_t)e1 * kRadial + 4);
    const f32x4 xv0 = __builtin_nontemporal_load(
        (const f32x4*)(x + (size_t)e0 * kEmb + sub * 4));
    const f32x4 xv1 = __builtin_nontemporal_load(
        (const f32x4*)(x + (size_t)e1 * kEmb + sub * 4));
    const f32x4 g0 = a0.x * w[0] + a0.y * w[1] + b0.x * w[2] +
                     b0.y * w[3] + c0.x * w[4] + c0.y * w[5];
    const f32x4 g1 = a1.x * w[0] + a1.y * w[1] + b1.x * w[2] +
                     b1.y * w[3] + c1.x * w[4] + c1.y * w[5];
    acc0 += g0 * xv0;
    acc1 += g1 * xv1;
  }
  if (i < end) {   // odd tail
    const int e0 = edgeIdx[i];
    const float2 a0 = *(const float2*)(rbf + (size_t)e0 * kRadial);
    const float2 b0 = *(const float2*)(rbf + (size_t)e0 * kRadial + 2);
    const float2 c0 = *(const float2*)(rbf + (size_t)e0 * kRadial + 4);
    const f32x4 xv0 = __builtin_nontemporal_load(
        (const f32x4*)(x + (size_t)e0 * kEmb + sub * 4));
    const f32x4 g0 = a0.x * w[0] + a0.y * w[1] + b0.x * w[2] +
                     b0.y * w[3] + c0.x * w[4] + c0.y * w[5];
    acc0 += g0 * xv0;
  }
  const f32x4 acc = acc0 + acc1;

  ushort4 hv;
  hv.x = f2h(acc.x);
  hv.y = f2h(acc.y);
  hv.z = f2h(acc.z);
  hv.w = f2h(acc.w);
  *(ushort4*)(pooled + (size_t)n * kEmb + sub * 4) = hv;
}

// ---------------------------------------------------------------------------
// Fused node MLP (R7 structure): wave-private fragment-order weight DMA
// (global_load_lds w16), counted vmcnt, no per-chunk barriers.
// ---------------------------------------------------------------------------
__global__ __launch_bounds__(256) void fused_mlp(
    const unsigned short* __restrict__ pooled,
    const unsigned short* __restrict__ WtUp,
    const unsigned short* __restrict__ WtM,
    const unsigned short* __restrict__ WtFin,
    const float* __restrict__ b_mlp, float* __restrict__ out) {
  __shared__ unsigned short act[64][266];   // odd word-pitch: conflict-light
  __shared__ unsigned short sB[2][8192];    // 2 x 16 KB, fragment order

  const int tid     = threadIdx.x;
  const int rowBase = blockIdx.x * 64;
  const int w    = tid >> 6;
  const int lane = tid & 63;
  const int lrow = lane & 15;
  const int kgrp = lane >> 4;

  // Stage pooled -> act (64 x 128 fp16).
#pragma unroll
  for (int p = 0; p < 4; ++p) {
    const int q = p * 256 + tid;
    const int r = q >> 4, c = q & 15;
    *(u32x4*)&act[r][c * 8] =
        *(const u32x4*)(pooled + (size_t)(rowBase + r) * kEmb + c * 8);
  }
  __syncthreads();

  for (int l = 0; l < 4; ++l) {
    const int nc = (l == 0) ? 4 : 8;
    const unsigned short* W = (l == 0) ? WtUp : WtM + (size_t)(l - 1) * 65536;

    // Preload bias into VGPRs and pin (keeps in-loop vmcnt counts exact).
    float bj[4] = {0.f, 0.f, 0.f, 0.f};
    if (l >= 1) {
      const float* bias = b_mlp + (size_t)(l - 1) * kOut;
#pragma unroll
      for (int j = 0; j < 4; ++j) bj[j] = bias[w * 64 + j * 16 + lrow];
      asm volatile("" ::"v"(bj[0]), "v"(bj[1]), "v"(bj[2]), "v"(bj[3]));
    }

    // Prologue: stage chunk 0 -> buf 0 (wave-private fragments).
#pragma unroll
    for (int j = 0; j < 4; ++j)
      __builtin_amdgcn_global_load_lds(
          (gvoid*)(W + w * 2048 + j * 512 + lane * 8),
          (lvoid*)&sB[0][w * 2048 + j * 512], 16, 0, 0);

    f32x4 acc[4][4];
#pragma unroll
    for (int i = 0; i < 4; ++i)
#pragma unroll
      for (int j = 0; j < 4; ++j) acc[i][j] = f32x4{0.f, 0.f, 0.f, 0.f};

    int buf = 0;
    for (int c = 0; c < nc; ++c) {
      if (c + 1 < nc) {
        const unsigned short* Wn = W + (size_t)(c + 1) * 8192;
#pragma unroll
        for (int j = 0; j < 4; ++j)
          __builtin_amdgcn_global_load_lds(
              (gvoid*)(Wn + w * 2048 + j * 512 + lane * 8),
              (lvoid*)&sB[buf ^ 1][w * 2048 + j * 512], 16, 0, 0);
        asm volatile("s_waitcnt vmcnt(4)" ::: "memory");  // chunk c landed
      } else {
        asm volatile("s_waitcnt vmcnt(0)" ::: "memory");
      }
      u32x4 a[4], b[4];
#pragma unroll
      for (int i = 0; i < 4; ++i)
        a[i] = *(const u32x4*)&act[i * 16 + lrow][c * 32 + kgrp * 8];
#pragma unroll
      for (int j = 0; j < 4; ++j)
        b[j] = *(const u32x4*)&sB[buf][w * 2048 + j * 512 + lane * 8];
      __builtin_amdgcn_s_setprio(1);
#pragma unroll
      for (int j = 0; j < 4; ++j)
#pragma unroll
        for (int i = 0; i < 4; ++i) mfma_f16(acc[i][j], a[i], b[j]);
      __builtin_amdgcn_s_setprio(0);
      buf ^= 1;
    }

    __syncthreads();   // all waves done reading act for this layer
#pragma unroll
    for (int j = 0; j < 4; ++j) {
      const int col = w * 64 + j * 16 + lrow;
#pragma unroll
      for (int i = 0; i < 4; ++i) {
#pragma unroll
        for (int r = 0; r < 4; ++r) {
          float v = acc[i][j][r];
          if (l >= 1) {
            v += bj[j];
            v = v / (1.f + __expf(-v));   // silu
          }
          act[i * 16 + kgrp * 4 + r][col] = f2h(v);
        }
      }
    }
    __syncthreads();
  }

  // Final projection: act[64,256] @ WtFin^T[16,256].
  // sPart inner dim MUST be 16 (epilogue writes cols 0..15). 16 KB = sB[1].
  unsigned short (*sWf)[266] = (unsigned short(*)[266]) & sB[0][0];  // 8.5 KB
  float (*sPart)[64][16]     = (float(*)[64][16]) & sB[1][0];        // 16 KB
#pragma unroll
  for (int p = 0; p < 2; ++p) {
    const int q = p * 256 + tid;
    const int n = q >> 5, c = q & 31;
    *(u32x4*)&sWf[n][c * 8] = *(const u32x4*)(WtFin + (size_t)n * 256 + c * 8);
  }
  __syncthreads();

  f32x4 accF[4];
#pragma unroll
  for (int i = 0; i < 4; ++i) accF[i] = f32x4{0.f, 0.f, 0.f, 0.f};
#pragma unroll
  for (int s = 0; s < 2; ++s) {
    const int cc = w * 2 + s;
    const u32x4 b = *(const u32x4*)&sWf[lrow][cc * 32 + kgrp * 8];
#pragma unroll
    for (int i = 0; i < 4; ++i) {
      const u32x4 a = *(const u32x4*)&act[i * 16 + lrow][cc * 32 + kgrp * 8];
      mfma_f16(accF[i], a, b);
    }
  }
#pragma unroll
  for (int i = 0; i < 4; ++i)
#pragma unroll
    for (int r = 0; r < 4; ++r)
      sPart[w][i * 16 + kgrp * 4 + r][lrow] = accF[i][r];
  __syncthreads();

  for (int q = tid; q < 64 * kTargets; q += 256) {
    const int r = q / kTargets, t = q % kTargets;
    out[(size_t)(rowBase + r) * kTargets + t] =
        sPart[0][r][t] + sPart[1][r][t] + sPart[2][r][t] + sPart[3][r][t];
  }
}

// ---------------------------------------------------------------------------
extern "C" void kernel_launch(void* const* d_in, const int* in_sizes, int n_in,
                              void* d_out, int out_size, void* d_ws, size_t ws_size,
                              hipStream_t stream) {
  const float* x      = (const float*)d_in[1];
  const float* rbf    = (const float*)d_in[2];
  const int*   idnb   = (const int*)d_in[3];
  const float* W_rbf  = (const float*)d_in[4];
  const float* W_up   = (const float*)d_in[5];
  const float* W_mlp  = (const float*)d_in[6];
  const float* b_mlp  = (const float*)d_in[7];
  const float* W_fin  = (const float*)d_in[8];
  float* out = (float*)d_out;

  char* wp = (char*)d_ws;
  auto alloc = [&](size_t bytes) -> void* {
    void* r = wp;
    wp += (bytes + 255) & ~(size_t)255;
    return r;
  };
  unsigned short* pooled = (unsigned short*)alloc((size_t)kNodes * kEmb * 2);
  unsigned short* WtUp   = (unsigned short*)alloc(32768 * 2);
  unsigned short* WtM    = (unsigned short*)alloc(3 * 65536 * 2);
  unsigned short* WtFin  = (unsigned short*)alloc(16 * 256 * 2);
  int* counts  = (int*)alloc((size_t)kNodes * 4);
  int* offs    = (int*)alloc((size_t)(kNodes + 8) * 4);
  int* next    = (int*)alloc((size_t)kNodes * 4);
  int* edgeIdx = (int*)alloc((size_t)kEdges * 4);
  int* bsum    = (int*)alloc(256 * 4);

  constexpr int nScanBlk = (kNodes + 255) / 256;  // 157
  constexpr int prepElems = 32768 + 3 * 65536 + 16 * 256;  // 233472

  // 1: weight images + counts zeroing.
  prep_weights<<<(prepElems + 255) / 256, 256, 0, stream>>>(
      W_up, W_mlp, W_fin, WtUp, WtM, WtFin, counts);
  // 2-5: CSR build (all multi-block).
  hist_kernel<<<kEdges / 256, 256, 0, stream>>>(idnb, counts);
  scan_pass1<<<nScanBlk, 256, 0, stream>>>(counts, bsum);
  scan_pass3<<<nScanBlk, 256, 0, stream>>>(counts, bsum, offs, next, nScanBlk);
  fill_kernel<<<kEdges / 256, 256, 0, stream>>>(idnb, next, edgeIdx);
  // 6: gather (high occupancy, 2-wide dual-chain).
  gather_kernel<<<kNodes / 8, 256, 0, stream>>>(x, rbf, offs, edgeIdx, W_rbf,
                                                pooled);
  // 7: fused node MLP + projection.
  fused_mlp<<<kNodes / 64, 256, 0, stream>>>(pooled, WtUp, WtM, WtFin, b_mlp,
                                             out);
}